// Round 4
// baseline (176.844 us; speedup 1.0000x reference)
//
#include <hip/hip_runtime.h>
#include <math.h>

#define T_ 30
#define C_ 512
#define N_ 784     // 28*28
#define NP_ 832    // padded n for aT / xh/xl rows (52 strips of 16)
#define NB_ 800    // padded n for xb_cn cols (25 ksteps of 32)
#define EPSV 1e-12f

typedef __attribute__((ext_vector_type(8))) short bf16x8;
typedef __attribute__((ext_vector_type(4))) float f32x4;

__device__ __forceinline__ unsigned short f2bf(float f) {
    union { float f; unsigned int u; } v; v.f = f;
    unsigned int r = (v.u + 0x7FFFu + ((v.u >> 16) & 1u)) >> 16;  // RNE
    return (unsigned short)r;
}
__device__ __forceinline__ float bf2f(unsigned short h) {
    union { unsigned int u; float f; } v; v.u = ((unsigned int)h) << 16;
    return v.f;
}

// wh/wl: split-precision bf16 of w, layout [k][c]
__global__ void k_prep(const float* __restrict__ w, unsigned short* __restrict__ wh,
                       unsigned short* __restrict__ wl) {
    int idx = blockIdx.x * 256 + threadIdx.x;  // 0..32767
    float v = w[idx];
    unsigned short h = f2bf(v);
    wh[idx] = h;
    wl[idx] = f2bf(v - bf2f(h));
}

// One-shot transpose/convert + sumsq. grid (13 n-tiles, 8 c-tiles, 30 t), 256 thr.
// Writes: xh/xl [t][n:832][c:512] bf16 (zero-padded rows), xcn [t][c][n:800] bf16,
// atomicAdd sumsq[t][n].
__global__ __launch_bounds__(256) void k_trans(
    const float* __restrict__ x, unsigned short* __restrict__ xh,
    unsigned short* __restrict__ xl, unsigned short* __restrict__ xcn,
    float* __restrict__ sumsq)
{
    __shared__ float sx[64][65];
    __shared__ float wred[4][64];
    int nt = blockIdx.x, ct = blockIdx.y, t = blockIdx.z;
    int n0 = nt * 64, c0 = ct * 64;
    int tid = threadIdx.x;
    int cr = tid >> 4, li = tid & 15;   // cr: 16 c-rows, li: n-quad
    int w = tid >> 6;
    float ss[4] = {0.f, 0.f, 0.f, 0.f};

    #pragma unroll
    for (int j = 0; j < 4; ++j) {
        int cl = j * 16 + cr;
        int n = n0 + li * 4;
        float4 q = make_float4(0.f, 0.f, 0.f, 0.f);
        if (n < N_)  // N_ multiple of 4: full or nothing
            q = *reinterpret_cast<const float4*>(x + ((size_t)t * C_ + c0 + cl) * N_ + n);
        ss[0] = fmaf(q.x, q.x, ss[0]); ss[1] = fmaf(q.y, q.y, ss[1]);
        ss[2] = fmaf(q.z, q.z, ss[2]); ss[3] = fmaf(q.w, q.w, ss[3]);
        sx[cl][li * 4 + 0] = q.x; sx[cl][li * 4 + 1] = q.y;
        sx[cl][li * 4 + 2] = q.z; sx[cl][li * 4 + 3] = q.w;
    }
    #pragma unroll
    for (int i = 0; i < 4; ++i) {
        ss[i] += __shfl_xor(ss[i], 16, 64);
        ss[i] += __shfl_xor(ss[i], 32, 64);
    }
    if (((tid >> 4) & 3) == 0) {   // quad==0 lanes
        wred[w][li * 4 + 0] = ss[0]; wred[w][li * 4 + 1] = ss[1];
        wred[w][li * 4 + 2] = ss[2]; wred[w][li * 4 + 3] = ss[3];
    }
    __syncthreads();
    if (tid < 64 && n0 + tid < N_) {
        float s = wred[0][tid] + wred[1][tid] + wred[2][tid] + wred[3][tid];
        atomicAdd(&sumsq[t * N_ + n0 + tid], s);
    }
    // write xh/xl [n][c]: thread -> c-seg li2*4, n-rows nr + j*16
    {
        int li2 = tid & 15, nr = tid >> 4;
        #pragma unroll
        for (int j = 0; j < 4; ++j) {
            int nl = nr + j * 16;
            ushort4 h, l;
            float v0 = sx[li2 * 4 + 0][nl], v1 = sx[li2 * 4 + 1][nl];
            float v2 = sx[li2 * 4 + 2][nl], v3 = sx[li2 * 4 + 3][nl];
            h.x = f2bf(v0); l.x = f2bf(v0 - bf2f(h.x));
            h.y = f2bf(v1); l.y = f2bf(v1 - bf2f(h.y));
            h.z = f2bf(v2); l.z = f2bf(v2 - bf2f(h.z));
            h.w = f2bf(v3); l.w = f2bf(v3 - bf2f(h.w));
            size_t o = ((size_t)t * NP_ + n0 + nl) * C_ + c0 + li2 * 4;
            *reinterpret_cast<ushort4*>(xh + o) = h;
            *reinterpret_cast<ushort4*>(xl + o) = l;
        }
    }
    // write xcn [c][n]: thread -> c-row j*16+cr, n-seg li*4
    #pragma unroll
    for (int j = 0; j < 4; ++j) {
        int cl = j * 16 + cr;
        int n = n0 + li * 4;
        if (n < NB_) {
            ushort4 h;
            h.x = f2bf(sx[cl][li * 4 + 0]); h.y = f2bf(sx[cl][li * 4 + 1]);
            h.z = f2bf(sx[cl][li * 4 + 2]); h.w = f2bf(sx[cl][li * 4 + 3]);
            *reinterpret_cast<ushort4*>(xcn + ((size_t)t * C_ + c0 + cl) * NB_ + n) = h;
        }
    }
}

// Barrier-free, LDS-free assign: 1 wave per block, grid (52, 30).
// Wave: 16 n (lid) x 64 k (4 mt-tiles), c streamed 16 ksteps of 32.
__global__ __launch_bounds__(64) void k_assign(
    const unsigned short* __restrict__ xh, const unsigned short* __restrict__ xl,
    const unsigned short* __restrict__ wh, const unsigned short* __restrict__ wl,
    const float* __restrict__ b, const float* __restrict__ sumsq,
    unsigned short* __restrict__ aT, float* __restrict__ asum)
{
    int t = blockIdx.y;
    int n0 = blockIdx.x * 16;
    int L = threadIdx.x & 63, lid = L & 15, quad = L >> 4;
    int n_lane = n0 + lid;

    f32x4 acc[4];
    #pragma unroll
    for (int mt = 0; mt < 4; ++mt)
        #pragma unroll
        for (int r = 0; r < 4; ++r) acc[mt][r] = 0.f;

    const unsigned short* bp = xh + ((size_t)t * NP_ + n_lane) * C_ + quad * 8;
    const unsigned short* blp = xl + ((size_t)t * NP_ + n_lane) * C_ + quad * 8;

    #pragma unroll 4
    for (int ks = 0; ks < 16; ++ks) {
        int cs = ks * 32;
        bf16x8 bh = *reinterpret_cast<const bf16x8*>(bp + cs);
        bf16x8 bl = *reinterpret_cast<const bf16x8*>(blp + cs);
        #pragma unroll
        for (int mt = 0; mt < 4; ++mt) {
            const unsigned short* ar = wh + (size_t)(mt * 16 + lid) * C_ + cs + quad * 8;
            const unsigned short* alr = wl + (size_t)(mt * 16 + lid) * C_ + cs + quad * 8;
            bf16x8 ah = *reinterpret_cast<const bf16x8*>(ar);
            bf16x8 al = *reinterpret_cast<const bf16x8*>(alr);
            acc[mt] = __builtin_amdgcn_mfma_f32_16x16x32_bf16(ah, bh, acc[mt], 0, 0, 0);
            acc[mt] = __builtin_amdgcn_mfma_f32_16x16x32_bf16(al, bh, acc[mt], 0, 0, 0);
            acc[mt] = __builtin_amdgcn_mfma_f32_16x16x32_bf16(ah, bl, acc[mt], 0, 0, 0);
        }
    }

    bool valid = n_lane < N_;
    float inv = 0.f;
    if (valid) {
        float s = sumsq[t * N_ + n_lane];
        inv = 1.0f / fmaxf(sqrtf(s), EPSV);
    }
    // softmax over k (lane's k = mt*16 + quad*4 + r; same-n lanes differ only in quad)
    f32x4 bv[4];
    #pragma unroll
    for (int mt = 0; mt < 4; ++mt)
        bv[mt] = *reinterpret_cast<const f32x4*>(b + mt * 16 + quad * 4);
    float lg[16];
    float mx = -1e30f;
    #pragma unroll
    for (int mt = 0; mt < 4; ++mt)
        #pragma unroll
        for (int r = 0; r < 4; ++r) {
            float v = fmaf(acc[mt][r], inv, bv[mt][r]);
            lg[mt * 4 + r] = v;
            mx = fmaxf(mx, v);
        }
    mx = fmaxf(mx, __shfl_xor(mx, 16, 64));
    mx = fmaxf(mx, __shfl_xor(mx, 32, 64));
    float se = 0.f;
    #pragma unroll
    for (int u = 0; u < 16; ++u) { lg[u] = __expf(lg[u] - mx); se += lg[u]; }
    se += __shfl_xor(se, 16, 64);
    se += __shfl_xor(se, 32, 64);
    float rs = 1.0f / se;

    size_t abase = (size_t)t * 64 * NP_ + n_lane;
    #pragma unroll
    for (int mt = 0; mt < 4; ++mt)
        #pragma unroll
        for (int r = 0; r < 4; ++r) {
            int k = mt * 16 + quad * 4 + r;
            float a = lg[mt * 4 + r] * rs;
            aT[abase + (size_t)k * NP_] = valid ? f2bf(a * inv) : (unsigned short)0;
            float ak = valid ? a : 0.f;
            ak += __shfl_xor(ak, 1, 64); ak += __shfl_xor(ak, 2, 64);
            ak += __shfl_xor(ak, 4, 64); ak += __shfl_xor(ak, 8, 64);
            if (lid == 0) atomicAdd(&asum[t * 64 + k], ak);
        }
}

// Barrier-free, LDS-free vlad: 1 wave per block, grid (32, 30).
// Wave: 16 c (lid) x 64 k (4 mt-tiles), n streamed 25 ksteps of 32.
__global__ __launch_bounds__(64) void k_vlad(
    const unsigned short* __restrict__ xcn, const unsigned short* __restrict__ aT,
    const float* __restrict__ asum, const float* __restrict__ cent,
    float* __restrict__ vlad)
{
    int t = blockIdx.y;
    int L = threadIdx.x & 63, lid = L & 15, quad = L >> 4;
    int c = blockIdx.x * 16 + lid;

    f32x4 acc[4];
    #pragma unroll
    for (int mt = 0; mt < 4; ++mt)
        #pragma unroll
        for (int r = 0; r < 4; ++r) acc[mt][r] = 0.f;

    const unsigned short* xr = xcn + ((size_t)t * C_ + c) * NB_ + quad * 8;
    const unsigned short* ab = aT + (size_t)t * 64 * NP_ + quad * 8;

    #pragma unroll 5
    for (int s = 0; s < 25; ++s) {
        int nb = s * 32;
        bf16x8 bb = *reinterpret_cast<const bf16x8*>(xr + nb);
        #pragma unroll
        for (int mt = 0; mt < 4; ++mt) {
            bf16x8 af = *reinterpret_cast<const bf16x8*>(ab + (size_t)(mt * 16 + lid) * NP_ + nb);
            acc[mt] = __builtin_amdgcn_mfma_f32_16x16x32_bf16(af, bb, acc[mt], 0, 0, 0);
        }
    }
    #pragma unroll
    for (int mt = 0; mt < 4; ++mt)
        #pragma unroll
        for (int r = 0; r < 4; ++r) {
            int k = mt * 16 + quad * 4 + r;
            float v = acc[mt][r] - asum[t * 64 + k] * cent[k * 512 + c];
            vlad[((size_t)t * 64 + k) * 512 + c] = v;
        }
}

__global__ void k_intra(const float* __restrict__ vlad, float* __restrict__ inv_intra,
                        float* __restrict__ g) {
    int w = blockIdx.x * 4 + (threadIdx.x >> 6);  // t*64+k
    int lane = threadIdx.x & 63;
    const float* vp = vlad + (size_t)w * 512 + lane;
    float s = 0.f;
    #pragma unroll
    for (int j = 0; j < 8; ++j) { float v = vp[j * 64]; s = fmaf(v, v, s); }
    #pragma unroll
    for (int m = 32; m >= 1; m >>= 1) s += __shfl_xor(s, m, 64);
    float inv = 1.0f / fmaxf(sqrtf(s), EPSV);
    if (lane == 0) { inv_intra[w] = inv; g[w] = s * inv * inv; }
}

// out[k*512+c] = sum_t vlad*inv_intra*inv_g; inv_g computed in-block from g.
__global__ void k_out(const float* __restrict__ vlad, const float* __restrict__ inv_intra,
                      const float* __restrict__ g, float* __restrict__ out) {
    __shared__ float sinv[T_];
    int tid = threadIdx.x;
    if (tid < T_) {
        float s = 0.f;
        #pragma unroll 8
        for (int k = 0; k < 64; ++k) s += g[tid * 64 + k];
        sinv[tid] = 1.0f / fmaxf(sqrtf(s), EPSV);
    }
    __syncthreads();
    int idx = blockIdx.x * 256 + tid;  // k*512+c
    int k = idx >> 9;
    float s = 0.f;
    #pragma unroll 5
    for (int t = 0; t < T_; ++t)
        s += vlad[(size_t)t * 32768 + idx] * inv_intra[t * 64 + k] * sinv[t];
    out[idx] = s;
}

extern "C" void kernel_launch(void* const* d_in, const int* in_sizes, int n_in,
                              void* d_out, int out_size, void* d_ws, size_t ws_size,
                              hipStream_t stream) {
    const float* x    = (const float*)d_in[0];   // 30*512*784
    const float* cent = (const float*)d_in[1];   // 64*512
    const float* w    = (const float*)d_in[2];   // 64*512
    const float* b    = (const float*)d_in[3];   // 64
    float* out = (float*)d_out;

    char* p = (char*)d_ws;
    unsigned short* wh = (unsigned short*)p;  p += 65536;
    unsigned short* wl = (unsigned short*)p;  p += 65536;
    float* sumsq = (float*)p;                 p += 30 * 784 * 4;          // 94080
    float* asum  = (float*)p;                 p += 1920 * 4;              // 7680
    unsigned short* aT = (unsigned short*)p;  p += (size_t)30 * 64 * NP_ * 2;   // 3,194,880
    unsigned short* xh = (unsigned short*)p;  p += (size_t)30 * NP_ * C_ * 2;   // 25,559,040
    unsigned short* xl = (unsigned short*)p;  p += (size_t)30 * NP_ * C_ * 2;   // 25,559,040
    unsigned short* xcn = (unsigned short*)p; p += (size_t)30 * C_ * NB_ * 2;   // 24,576,000
    float* vlad = (float*)p;                  p += (size_t)983040 * 4;    // 3,932,160
    float* inv_intra = (float*)p;             p += 7680;
    float* g = (float*)p;                     p += 7680;
    // total ~= 83.1 MB

    k_prep<<<128, 256, 0, stream>>>(w, wh, wl);
    hipMemsetAsync(sumsq, 0, 30 * 784 * 4, stream);
    hipMemsetAsync(asum, 0, 1920 * 4, stream);
    k_trans<<<dim3(13, 8, T_), 256, 0, stream>>>(x, xh, xl, xcn, sumsq);
    k_assign<<<dim3(52, T_), 64, 0, stream>>>(xh, xl, wh, wl, b, sumsq, aT, asum);
    k_vlad<<<dim3(32, T_), 64, 0, stream>>>(xcn, aT, asum, cent, vlad);
    k_intra<<<480, 256, 0, stream>>>(vlad, inv_intra, g);
    k_out<<<128, 256, 0, stream>>>(vlad, inv_intra, g, out);
}

// Round 5
// 150.864 us; speedup vs baseline: 1.1722x; 1.1722x over previous
//
#include <hip/hip_runtime.h>
#include <math.h>

#define T_ 30
#define C_ 512
#define N_ 784      // 28*28 = 49 tiles of 16
#define NA_ 800     // aT row pitch (25 ksteps of 32)
#define XPITCH 520  // LDS stage row pitch in ushorts (16B-aligned rows, 2-way-max banks)
#define EPSV 1e-12f

typedef __attribute__((ext_vector_type(8))) short bf16x8;
typedef __attribute__((ext_vector_type(4))) float f32x4;

__device__ __forceinline__ unsigned short f2bf(float f) {
    union { float f; unsigned int u; } v; v.f = f;
    unsigned int r = (v.u + 0x7FFFu + ((v.u >> 16) & 1u)) >> 16;  // RNE
    return (unsigned short)r;
}
__device__ __forceinline__ float bf2f(unsigned short h) {
    union { unsigned int u; float f; } v; v.u = ((unsigned int)h) << 16;
    return v.f;
}

// wh/wl: split-precision bf16 of w, layout [k][c]
__global__ void k_prep(const float* __restrict__ w, unsigned short* __restrict__ wh,
                       unsigned short* __restrict__ wl) {
    int idx = blockIdx.x * 256 + threadIdx.x;  // 0..32767
    float v = w[idx];
    unsigned short h = f2bf(v);
    wh[idx] = h;
    wl[idx] = f2bf(v - bf2f(h));
}

// Fused invnorm + logits (3-product split-bf16 MFMA) + softmax + aT + asum.
// grid (49, 30), 256 thr. Block: 16 n x 64 k, c-reduction split over 4 waves.
__global__ __launch_bounds__(256) void k_assign(
    const float* __restrict__ x, const unsigned short* __restrict__ wh,
    const unsigned short* __restrict__ wl, const float* __restrict__ b,
    unsigned short* __restrict__ aT, float* __restrict__ asum)
{
    // stage: xh/xl [16 n][XPITCH c]; red (union, reused after MFMA): [4 w][16 n][68 k]
    __shared__ __align__(16) char smem[2 * 16 * XPITCH * 2];  // 33280 B >= red 17408 B
    unsigned short* xh = (unsigned short*)smem;
    unsigned short* xl = xh + 16 * XPITCH;
    float* red = (float*)smem;
    __shared__ float ssq[4][16];
    __shared__ float invl[16];

    int t = blockIdx.y, n0 = blockIdx.x * 16;
    int tid = threadIdx.x;
    int w = tid >> 6, L = tid & 63, lid = L & 15, quad = L >> 4;

    // ---- stage all 512 c x 16 n (transpose + hi/lo split), accumulate sumsq
    int nseg = (tid & 3) * 4;       // n offset 0/4/8/12
    int crow = tid >> 2;            // 0..63
    float ss0 = 0.f, ss1 = 0.f, ss2 = 0.f, ss3 = 0.f;
    #pragma unroll
    for (int p = 0; p < 8; ++p) {
        int c = p * 64 + crow;
        float4 q = *reinterpret_cast<const float4*>(
            x + ((size_t)t * C_ + c) * N_ + n0 + nseg);
        ss0 = fmaf(q.x, q.x, ss0); ss1 = fmaf(q.y, q.y, ss1);
        ss2 = fmaf(q.z, q.z, ss2); ss3 = fmaf(q.w, q.w, ss3);
        float vv[4] = {q.x, q.y, q.z, q.w};
        #pragma unroll
        for (int j = 0; j < 4; ++j) {
            unsigned short h = f2bf(vv[j]);
            xh[(nseg + j) * XPITCH + c] = h;
            xl[(nseg + j) * XPITCH + c] = f2bf(vv[j] - bf2f(h));
        }
    }
    // reduce sumsq over same-nseg lanes (stride-4 within wave)
    #pragma unroll
    for (int m = 4; m <= 32; m <<= 1) {
        ss0 += __shfl_xor(ss0, m, 64); ss1 += __shfl_xor(ss1, m, 64);
        ss2 += __shfl_xor(ss2, m, 64); ss3 += __shfl_xor(ss3, m, 64);
    }
    if (L < 4) {
        ssq[w][L * 4 + 0] = ss0; ssq[w][L * 4 + 1] = ss1;
        ssq[w][L * 4 + 2] = ss2; ssq[w][L * 4 + 3] = ss3;
    }
    __syncthreads();
    if (tid < 16) {
        float s = ssq[0][tid] + ssq[1][tid] + ssq[2][tid] + ssq[3][tid];
        invl[tid] = 1.0f / fmaxf(sqrtf(s), EPSV);
    }

    // ---- MFMA: wave w covers c in [w*128, w*128+128)
    f32x4 acc[4];
    #pragma unroll
    for (int mt = 0; mt < 4; ++mt)
        #pragma unroll
        for (int r = 0; r < 4; ++r) acc[mt][r] = 0.f;

    #pragma unroll
    for (int ks = 0; ks < 4; ++ks) {
        int cs = w * 128 + ks * 32;
        bf16x8 bh = *reinterpret_cast<const bf16x8*>(&xh[lid * XPITCH + cs + quad * 8]);
        bf16x8 bl = *reinterpret_cast<const bf16x8*>(&xl[lid * XPITCH + cs + quad * 8]);
        #pragma unroll
        for (int mt = 0; mt < 4; ++mt) {
            bf16x8 ah = *reinterpret_cast<const bf16x8*>(wh + (size_t)(mt * 16 + lid) * C_ + cs + quad * 8);
            bf16x8 al = *reinterpret_cast<const bf16x8*>(wl + (size_t)(mt * 16 + lid) * C_ + cs + quad * 8);
            acc[mt] = __builtin_amdgcn_mfma_f32_16x16x32_bf16(ah, bh, acc[mt], 0, 0, 0);
            acc[mt] = __builtin_amdgcn_mfma_f32_16x16x32_bf16(al, bh, acc[mt], 0, 0, 0);
            acc[mt] = __builtin_amdgcn_mfma_f32_16x16x32_bf16(ah, bl, acc[mt], 0, 0, 0);
        }
    }
    __syncthreads();   // stage memory now dead -> reuse as red
    {
        float* rp = red + w * (16 * 68);
        #pragma unroll
        for (int mt = 0; mt < 4; ++mt)
            *reinterpret_cast<f32x4*>(&rp[lid * 68 + mt * 16 + quad * 4]) = acc[mt];
    }
    __syncthreads();

    // ---- softmax: wave w handles n rows w*4..w*4+3; lane L = k
    float bk = b[L];
    float asl = 0.f;
    unsigned short av[4];
    #pragma unroll
    for (int i = 0; i < 4; ++i) {
        int n = w * 4 + i;
        float v = red[0 * 1088 + n * 68 + L] + red[1 * 1088 + n * 68 + L]
                + red[2 * 1088 + n * 68 + L] + red[3 * 1088 + n * 68 + L];
        float inv = invl[n];
        v = fmaf(v, inv, bk);
        float mx = v;
        #pragma unroll
        for (int m = 1; m <= 32; m <<= 1) mx = fmaxf(mx, __shfl_xor(mx, m, 64));
        float e = __expf(v - mx);
        float se = e;
        #pragma unroll
        for (int m = 1; m <= 32; m <<= 1) se += __shfl_xor(se, m, 64);
        float a = e / se;
        av[i] = f2bf(a * inv);
        asl += a;
    }
    atomicAdd(&asum[t * 64 + L], asl);
    ushort4 st; st.x = av[0]; st.y = av[1]; st.z = av[2]; st.w = av[3];
    *reinterpret_cast<ushort4*>(aT + ((size_t)t * 64 + L) * NA_ + n0 + w * 4) = st;
}

// vlad[t][k][c] = sum_n ahat[k][n]*x[c][n] - asum[k]*cent[k][c]; also g2[t][k]=sum_c v^2.
// grid (32, 30), 256 thr. Block: 16 c x 64 k; n-reduction split over 4 waves.
__global__ __launch_bounds__(256) void k_vlad(
    const float* __restrict__ x, const unsigned short* __restrict__ aT,
    const float* __restrict__ asum, const float* __restrict__ cent,
    float* __restrict__ vlad, float* __restrict__ g2)
{
    __shared__ float red[4][16 * 68];
    int t = blockIdx.y, c0 = blockIdx.x * 16;
    int tid = threadIdx.x;
    int w = tid >> 6, L = tid & 63, lid = L & 15, quad = L >> 4;

    f32x4 acc[4];
    #pragma unroll
    for (int mt = 0; mt < 4; ++mt)
        #pragma unroll
        for (int r = 0; r < 4; ++r) acc[mt][r] = 0.f;

    const float* xrow = x + ((size_t)t * C_ + c0 + lid) * N_;
    const unsigned short* ab = aT + (size_t)t * 64 * NA_;

    for (int s = w; s < 25; s += 4) {
        int nb = s * 32 + quad * 8;
        int nbc = nb > 776 ? 776 : nb;   // clamped lanes hit aT zeros
        float4 x0 = *reinterpret_cast<const float4*>(xrow + nbc);
        float4 x1 = *reinterpret_cast<const float4*>(xrow + nbc + 4);
        bf16x8 bb;
        bb[0] = (short)f2bf(x0.x); bb[1] = (short)f2bf(x0.y);
        bb[2] = (short)f2bf(x0.z); bb[3] = (short)f2bf(x0.w);
        bb[4] = (short)f2bf(x1.x); bb[5] = (short)f2bf(x1.y);
        bb[6] = (short)f2bf(x1.z); bb[7] = (short)f2bf(x1.w);
        #pragma unroll
        for (int mt = 0; mt < 4; ++mt) {
            bf16x8 af = *reinterpret_cast<const bf16x8*>(ab + (size_t)(mt * 16 + lid) * NA_ + nb);
            acc[mt] = __builtin_amdgcn_mfma_f32_16x16x32_bf16(af, bb, acc[mt], 0, 0, 0);
        }
    }
    {
        float* rp = &red[w][0];
        #pragma unroll
        for (int mt = 0; mt < 4; ++mt)
            *reinterpret_cast<f32x4*>(&rp[lid * 68 + mt * 16 + quad * 4]) = acc[mt];
    }
    __syncthreads();

    // epilogue: thread -> k = tid>>2, 4 c
    int k = tid >> 2, cs4 = (tid & 3) * 4;
    float as = asum[t * 64 + k];
    float4 cv = *reinterpret_cast<const float4*>(cent + k * C_ + c0 + cs4);
    float4 vout;
    float s2 = 0.f;
    #pragma unroll
    for (int j = 0; j < 4; ++j) {
        int cc = cs4 + j;
        float v = red[0][cc * 68 + k] + red[1][cc * 68 + k]
                + red[2][cc * 68 + k] + red[3][cc * 68 + k];
        v -= as * ((const float*)&cv)[j];
        ((float*)&vout)[j] = v;
        s2 = fmaf(v, v, s2);
    }
    *reinterpret_cast<float4*>(vlad + ((size_t)t * 64 + k) * C_ + c0 + cs4) = vout;
    s2 += __shfl_xor(s2, 1, 64);
    s2 += __shfl_xor(s2, 2, 64);
    if ((tid & 3) == 0) atomicAdd(&g2[t * 64 + k], s2);
}

// out[k*512+c] = sum_t vlad * inv_intra * inv_g  (norm factors from g2)
__global__ __launch_bounds__(256) void k_out(
    const float* __restrict__ vlad, const float* __restrict__ g2,
    float* __restrict__ out)
{
    __shared__ float intr[1920];
    __shared__ float gl[1920];
    __shared__ float sinv[T_];
    int tid = threadIdx.x;
    for (int i = tid; i < 1920; i += 256) {
        float s = g2[i];
        gl[i] = s;
        intr[i] = 1.0f / fmaxf(sqrtf(s), EPSV);
    }
    __syncthreads();
    if (tid < T_) {
        float s = 0.f;
        #pragma unroll 8
        for (int k = 0; k < 64; ++k) {
            float iv = intr[tid * 64 + k];
            s += gl[tid * 64 + k] * iv * iv;
        }
        sinv[tid] = 1.0f / fmaxf(sqrtf(s), EPSV);
    }
    __syncthreads();
    int idx = blockIdx.x * 256 + tid;  // k*512+c
    int k = idx >> 9;
    float s = 0.f;
    #pragma unroll 5
    for (int t = 0; t < T_; ++t)
        s += vlad[(size_t)t * 32768 + idx] * intr[t * 64 + k] * sinv[t];
    out[idx] = s;
}

extern "C" void kernel_launch(void* const* d_in, const int* in_sizes, int n_in,
                              void* d_out, int out_size, void* d_ws, size_t ws_size,
                              hipStream_t stream) {
    const float* x    = (const float*)d_in[0];   // 30*512*784
    const float* cent = (const float*)d_in[1];   // 64*512
    const float* w    = (const float*)d_in[2];   // 64*512
    const float* b    = (const float*)d_in[3];   // 64
    float* out = (float*)d_out;

    char* p = (char*)d_ws;
    unsigned short* wh = (unsigned short*)p;  p += 65536;
    unsigned short* wl = (unsigned short*)p;  p += 65536;
    float* asum = (float*)p;                  p += 1920 * 4;
    float* g2   = (float*)p;                  p += 1920 * 4;
    unsigned short* aT = (unsigned short*)p;  p += (size_t)T_ * 64 * NA_ * 2;  // 3,072,000
    float* vlad = (float*)p;                  p += (size_t)T_ * 64 * C_ * 4;   // 3,932,160
    // total ~= 7.2 MB

    k_prep<<<128, 256, 0, stream>>>(w, wh, wl);
    hipMemsetAsync(asum, 0, 2 * 1920 * 4, stream);            // asum + g2 (contiguous)
    hipMemsetAsync(aT, 0, (size_t)T_ * 64 * NA_ * 2, stream); // zero incl. n=784..800 tail
    k_assign<<<dim3(49, T_), 256, 0, stream>>>(x, wh, wl, b, aT, asum);
    k_vlad<<<dim3(32, T_), 256, 0, stream>>>(x, aT, asum, cent, vlad, g2);
    k_out<<<128, 256, 0, stream>>>(vlad, g2, out);
}